// Round 5
// baseline (1077.842 us; speedup 1.0000x reference)
//
#include <hip/hip_runtime.h>

#define N_USER   300000
#define M_ITEM   700000
#define N_NODES  (N_USER + M_ITEM)
#define DIM      64
#define N_EDGES  1200000
#define BATCH    4096

#define CAPROWS  65536    // compact rows per level (expected max ~38K)
#define CAPE     262144   // edges per level list (expected max ~45K)

// counter slots: [0..2] row counts lvl1..3 (must equal lvl index), [3..5] edge counts
#define C_E1 3
#define C_E2 4
#define C_E3 5

// ---------------------------------------------------------------------------
// Threefry2x32-20, JAX partitionable path (bit-exact, verified round 2):
// per element e: x0 = 0 + k0, x1 = e + k1; 20 rounds; bits = x0^x1.
// ---------------------------------------------------------------------------
__device__ __forceinline__ unsigned rotl32(unsigned x, int r) {
    return (x << r) | (x >> (32 - r));
}

__global__ void veff_kernel(const float* __restrict__ edge_vals,
                            float* __restrict__ veff) {
    int e = blockIdx.x * blockDim.x + threadIdx.x;
    if (e >= N_EDGES) return;
    unsigned ks[3] = {0u, 42u, 0u ^ 42u ^ 0x1BD11BDAu};
    unsigned x0 = ks[0];
    unsigned x1 = (unsigned)e + ks[1];
    const int rotA[4] = {13, 15, 26, 6};
    const int rotB[4] = {17, 29, 16, 24};
#pragma unroll
    for (int g = 0; g < 5; ++g) {
#pragma unroll
        for (int j = 0; j < 4; ++j) {
            int r = (g & 1) ? rotB[j] : rotA[j];
            x0 += x1;
            x1 = rotl32(x1, r);
            x1 ^= x0;
        }
        x0 += ks[(g + 1) % 3];
        x1 += ks[(g + 2) % 3] + (unsigned)(g + 1);
    }
    unsigned bits = x0 ^ x1;
    float u = __uint_as_float((bits >> 9) | 0x3F800000u) - 1.0f;
    veff[e] = (u >= 0.1f) ? edge_vals[e] * (1.0f / 0.9f) : 0.0f;
}

// ---------------------------------------------------------------------------
// Marking: idempotent plain stores of -2. No allocation, no row zeroing.
// ---------------------------------------------------------------------------
__global__ void seed_mark_kernel(const int* __restrict__ users,
                                 const int* __restrict__ items,
                                 int* __restrict__ c1, int* __restrict__ c2,
                                 int* __restrict__ c3) {
    int t = blockIdx.x * blockDim.x + threadIdx.x;
    if (t >= 2 * BATCH) return;
    int node = (t < BATCH) ? users[t] : (N_USER + items[t - BATCH]);
    c3[node] = -2;
    c2[node] = -2;
    c1[node] = -2;
}

// level-3 frontier: edges into c3-marked nodes; mark srcs into c2 and c1
__global__ void markA_kernel(const int* __restrict__ esrc, const int* __restrict__ edst,
                             const float* __restrict__ veff,
                             const int* __restrict__ c3,
                             int* __restrict__ c2, int* __restrict__ c1,
                             int* __restrict__ el_src, int* __restrict__ el_gd,
                             float* __restrict__ el_v, int* __restrict__ cnt) {
    int e = blockIdx.x * blockDim.x + threadIdx.x;
    if (e >= N_EDGES) return;
    int d = edst[e];
    if (c3[d] == -1) return;
    float v = veff[e];
    if (v == 0.0f) return;
    int s = esrc[e];
    int pos = atomicAdd(&cnt[C_E3], 1);
    if (pos < CAPE) { el_src[pos] = s; el_gd[pos] = d; el_v[pos] = v; }
    c2[s] = -2;
    c1[s] = -2;
}

// level-2 frontier: edges into c2-marked nodes; mark srcs into c1
__global__ void markB_kernel(const int* __restrict__ esrc, const int* __restrict__ edst,
                             const float* __restrict__ veff,
                             const int* __restrict__ c2, int* __restrict__ c1,
                             int* __restrict__ el_src, int* __restrict__ el_gd,
                             float* __restrict__ el_v, int* __restrict__ cnt) {
    int e = blockIdx.x * blockDim.x + threadIdx.x;
    if (e >= N_EDGES) return;
    int d = edst[e];
    if (c2[d] == -1) return;
    float v = veff[e];
    if (v == 0.0f) return;
    int s = esrc[e];
    int pos = atomicAdd(&cnt[C_E2], 1);
    if (pos < CAPE) { el_src[pos] = s; el_gd[pos] = d; el_v[pos] = v; }
    c1[s] = -2;
}

// level-1 frontier: edges into c1-marked nodes (sources come from raw inputs)
__global__ void markC_kernel(const int* __restrict__ esrc, const int* __restrict__ edst,
                             const float* __restrict__ veff,
                             const int* __restrict__ c1,
                             int* __restrict__ el_src, int* __restrict__ el_gd,
                             float* __restrict__ el_v, int* __restrict__ cnt) {
    int e = blockIdx.x * blockDim.x + threadIdx.x;
    if (e >= N_EDGES) return;
    int d = edst[e];
    if (c1[d] == -1) return;
    float v = veff[e];
    if (v == 0.0f) return;
    int pos = atomicAdd(&cnt[C_E1], 1);
    if (pos < CAPE) { el_src[pos] = esrc[e]; el_gd[pos] = d; el_v[pos] = v; }
}

// ---------------------------------------------------------------------------
// Assignment: -2 -> compact index. One writer per entry; maps final afterward.
// cmaps = c1 base; c1,c2,c3 contiguous; lvl = i / N_NODES matches cnt slot.
// ---------------------------------------------------------------------------
__global__ void assign_kernel(int* __restrict__ cmaps, int* __restrict__ cnt) {
    int i = blockIdx.x * blockDim.x + threadIdx.x;
    if (i >= 3 * N_NODES) return;
    if (cmaps[i] == -2) {
        int lvl = i / N_NODES;
        int idx = atomicAdd(&cnt[lvl], 1);
        cmaps[i] = (idx < CAPROWS) ? idx : -3;  // defensive; never hit at these sizes
    }
}

// ---------------------------------------------------------------------------
// Compact scatter-SpMMs into pre-zeroed emb buffers. 16 threads/edge, float4.
// ---------------------------------------------------------------------------
__global__ void comp_inputs_kernel(const float* __restrict__ src_user,
                                   const float* __restrict__ src_item,
                                   const int* __restrict__ c1,
                                   const int* __restrict__ el_src,
                                   const int* __restrict__ el_gd,
                                   const float* __restrict__ el_v,
                                   const int* __restrict__ cnt,
                                   float* __restrict__ emb1) {
    int ne = min(cnt[C_E1], CAPE);
    int total = ne * 16;
    for (int t = blockIdx.x * blockDim.x + threadIdx.x; t < total;
         t += gridDim.x * blockDim.x) {
        int e = t >> 4;
        int c = (t & 15) << 2;
        int s = el_src[e];
        int dr = c1[el_gd[e]];
        if (dr < 0) continue;  // defensive
        float v = el_v[e];
        const float* srow = (s < N_USER) ? (src_user + (size_t)s * DIM)
                                         : (src_item + (size_t)(s - N_USER) * DIM);
        float4 x = *(const float4*)(srow + c);
        float* drow = emb1 + (size_t)dr * DIM + c;
        atomicAdd(drow + 0, v * x.x);
        atomicAdd(drow + 1, v * x.y);
        atomicAdd(drow + 2, v * x.z);
        atomicAdd(drow + 3, v * x.w);
    }
}

__global__ void comp_level_kernel(const float* __restrict__ srcEmb,
                                  const int* __restrict__ cs,   // src-level map
                                  const int* __restrict__ cd,   // dst-level map
                                  const int* __restrict__ el_src,
                                  const int* __restrict__ el_gd,
                                  const float* __restrict__ el_v,
                                  const int* __restrict__ cnt, int slot,
                                  float* __restrict__ outEmb) {
    int ne = min(cnt[slot], CAPE);
    int total = ne * 16;
    for (int t = blockIdx.x * blockDim.x + threadIdx.x; t < total;
         t += gridDim.x * blockDim.x) {
        int e = t >> 4;
        int c = (t & 15) << 2;
        int sr = cs[el_src[e]];
        int dr = cd[el_gd[e]];
        if (sr < 0 || dr < 0) continue;  // defensive
        float v = el_v[e];
        float4 x = *(const float4*)(srcEmb + (size_t)sr * DIM + c);
        float* drow = outEmb + (size_t)dr * DIM + c;
        atomicAdd(drow + 0, v * x.x);
        atomicAdd(drow + 1, v * x.y);
        atomicAdd(drow + 2, v * x.z);
        atomicAdd(drow + 3, v * x.w);
    }
}

// ---------------------------------------------------------------------------
// Fused extraction + pooling + ratings. One 64-lane wave per batch element.
// ---------------------------------------------------------------------------
__global__ void out_fused_kernel(const float* __restrict__ user_emb,
                                 const float* __restrict__ item_emb,
                                 const int* __restrict__ users,
                                 const int* __restrict__ items,
                                 const int* __restrict__ c1, const int* __restrict__ c2,
                                 const int* __restrict__ c3,
                                 const float* __restrict__ emb1,
                                 const float* __restrict__ emb2,
                                 const float* __restrict__ emb3,
                                 float* __restrict__ ratings,
                                 float* __restrict__ inter,
                                 float* __restrict__ inter_layers) {
    int b = blockIdx.x * 4 + (threadIdx.x >> 6);
    int d = threadIdx.x & 63;
    if (b >= BATCH) return;
    int un = users[b];
    int in_node = N_USER + items[b];

    // all sampled nodes are seeded+assigned; max() is a no-cost safety clamp
    int r1u = max(c1[un], 0), r1i = max(c1[in_node], 0);
    int r2u = max(c2[un], 0), r2i = max(c2[in_node], 0);
    int r3u = max(c3[un], 0), r3i = max(c3[in_node], 0);

    float u0 = user_emb[(size_t)un * DIM + d];
    float i0 = item_emb[(size_t)items[b] * DIM + d];
    float u1 = emb1[(size_t)r1u * DIM + d];
    float i1 = emb1[(size_t)r1i * DIM + d];
    float u2 = emb2[(size_t)r2u * DIM + d];
    float i2 = emb2[(size_t)r2i * DIM + d];
    float u3 = emb3[(size_t)r3u * DIM + d];
    float i3 = emb3[(size_t)r3i * DIM + d];

    size_t base = (size_t)b * 4 * DIM + d;
    inter_layers[base + 0 * DIM] = u0 * i0;
    inter_layers[base + 1 * DIM] = u1 * i1;
    inter_layers[base + 2 * DIM] = u2 * i2;
    inter_layers[base + 3 * DIM] = u3 * i3;

    float lu = (u0 + u1 + u2 + u3) * 0.25f;
    float li = (i0 + i1 + i2 + i3) * 0.25f;
    float p = lu * li;
    inter[(size_t)b * DIM + d] = p;
    float s = p;
#pragma unroll
    for (int off = 32; off > 0; off >>= 1) s += __shfl_down(s, off, 64);
    if (d == 0) ratings[b] = 1.0f / (1.0f + expf(-s));
}

// ---------------------------------------------------------------------------
extern "C" void kernel_launch(void* const* d_in, const int* in_sizes, int n_in,
                              void* d_out, int out_size, void* d_ws, size_t ws_size,
                              hipStream_t stream) {
    const float* user_emb  = (const float*)d_in[0];
    const float* item_emb  = (const float*)d_in[1];
    const float* edge_vals = (const float*)d_in[2];
    const int*   edge_src  = (const int*)d_in[3];
    const int*   edge_dst  = (const int*)d_in[4];
    const int*   users     = (const int*)d_in[5];
    const int*   items     = (const int*)d_in[6];

    float* out          = (float*)d_out;
    float* ratings      = out;                       // [BATCH]
    float* inter        = out + BATCH;               // [BATCH, DIM]
    float* inter_layers = out + BATCH + BATCH * DIM; // [BATCH, 4, DIM]

    char* ws = (char*)d_ws;
    size_t off = 0;
    int* c1 = (int*)(ws + off); off += (size_t)N_NODES * sizeof(int);
    int* c2 = (int*)(ws + off); off += (size_t)N_NODES * sizeof(int);
    int* c3 = (int*)(ws + off); off += (size_t)N_NODES * sizeof(int);
    float* emb1 = (float*)(ws + off); off += (size_t)CAPROWS * DIM * sizeof(float);
    float* emb2 = (float*)(ws + off); off += (size_t)CAPROWS * DIM * sizeof(float);
    float* emb3 = (float*)(ws + off); off += (size_t)CAPROWS * DIM * sizeof(float);
    float* veff = (float*)(ws + off); off += (size_t)N_EDGES * sizeof(float);
    int* el1_src = (int*)(ws + off); off += CAPE * sizeof(int);
    int* el1_gd  = (int*)(ws + off); off += CAPE * sizeof(int);
    float* el1_v = (float*)(ws + off); off += CAPE * sizeof(float);
    int* el2_src = (int*)(ws + off); off += CAPE * sizeof(int);
    int* el2_gd  = (int*)(ws + off); off += CAPE * sizeof(int);
    float* el2_v = (float*)(ws + off); off += CAPE * sizeof(float);
    int* el3_src = (int*)(ws + off); off += CAPE * sizeof(int);
    int* el3_gd  = (int*)(ws + off); off += CAPE * sizeof(int);
    float* el3_v = (float*)(ws + off); off += CAPE * sizeof(float);
    int* cnt = (int*)(ws + off); off += 16 * sizeof(int);

    const dim3 blk(256);
    const dim3 egrid((N_EDGES + 255) / 256);

    // bulk init: maps -1 (c1..c3 contiguous), emb rows 0 (emb1..3 contiguous), cnt 0
    hipMemsetAsync(c1, 0xFF, 3 * (size_t)N_NODES * sizeof(int), stream);
    hipMemsetAsync(emb1, 0, 3 * (size_t)CAPROWS * DIM * sizeof(float), stream);
    hipMemsetAsync(cnt, 0, 16 * sizeof(int), stream);

    veff_kernel<<<egrid, blk, 0, stream>>>(edge_vals, veff);

    seed_mark_kernel<<<(2 * BATCH + 255) / 256, blk, 0, stream>>>(
        users, items, c1, c2, c3);

    markA_kernel<<<egrid, blk, 0, stream>>>(edge_src, edge_dst, veff, c3, c2, c1,
                                            el3_src, el3_gd, el3_v, cnt);
    markB_kernel<<<egrid, blk, 0, stream>>>(edge_src, edge_dst, veff, c2, c1,
                                            el2_src, el2_gd, el2_v, cnt);
    markC_kernel<<<egrid, blk, 0, stream>>>(edge_src, edge_dst, veff, c1,
                                            el1_src, el1_gd, el1_v, cnt);

    assign_kernel<<<(3 * N_NODES + 255) / 256, blk, 0, stream>>>(c1, cnt);

    comp_inputs_kernel<<<1024, blk, 0, stream>>>(user_emb, item_emb, c1,
                                                 el1_src, el1_gd, el1_v, cnt, emb1);
    comp_level_kernel<<<1024, blk, 0, stream>>>(emb1, c1, c2,
                                                el2_src, el2_gd, el2_v, cnt, C_E2, emb2);
    comp_level_kernel<<<1024, blk, 0, stream>>>(emb2, c2, c3,
                                                el3_src, el3_gd, el3_v, cnt, C_E3, emb3);

    out_fused_kernel<<<BATCH / 4, blk, 0, stream>>>(
        user_emb, item_emb, users, items, c1, c2, c3, emb1, emb2, emb3,
        ratings, inter, inter_layers);
}

// Round 6
// 205.219 us; speedup vs baseline: 5.2521x; 5.2521x over previous
//
#include <hip/hip_runtime.h>

#define N_USER   300000
#define M_ITEM   700000
#define N_NODES  (N_USER + M_ITEM)
#define DIM      64
#define N_EDGES  1200000
#define BATCH    4096

#define POOLROWS 131072                 // pooled compact rows across all 3 levels (need ~66K)
#define TOT3     (3 * N_NODES)          // 3,000,000 map entries
#define SCHUNK   4096                   // entries per scan block (256 thr x 16)
#define NBLK     ((TOT3 + SCHUNK - 1) / SCHUNK)  // 733

// ---------------------------------------------------------------------------
// Threefry2x32-20, JAX partitionable path (bit-exact, verified round 2):
// per element e: x0 = 0 + k0, x1 = e + k1; 20 rounds; bits = x0^x1.
// ---------------------------------------------------------------------------
__device__ __forceinline__ unsigned rotl32(unsigned x, int r) {
    return (x << r) | (x >> (32 - r));
}

__global__ void veff_kernel(const float* __restrict__ edge_vals,
                            float* __restrict__ veff) {
    int e = blockIdx.x * blockDim.x + threadIdx.x;
    if (e >= N_EDGES) return;
    unsigned ks[3] = {0u, 42u, 0u ^ 42u ^ 0x1BD11BDAu};
    unsigned x0 = ks[0];
    unsigned x1 = (unsigned)e + ks[1];
    const int rotA[4] = {13, 15, 26, 6};
    const int rotB[4] = {17, 29, 16, 24};
#pragma unroll
    for (int g = 0; g < 5; ++g) {
#pragma unroll
        for (int j = 0; j < 4; ++j) {
            int r = (g & 1) ? rotB[j] : rotA[j];
            x0 += x1;
            x1 = rotl32(x1, r);
            x1 ^= x0;
        }
        x0 += ks[(g + 1) % 3];
        x1 += ks[(g + 2) % 3] + (unsigned)(g + 1);
    }
    unsigned bits = x0 ^ x1;
    float u = __uint_as_float((bits >> 9) | 0x3F800000u) - 1.0f;
    veff[e] = (u >= 0.1f) ? edge_vals[e] * (1.0f / 0.9f) : 0.0f;
}

// ---------------------------------------------------------------------------
// Marking: idempotent plain stores of -2 only. No atomics, no lists.
// ---------------------------------------------------------------------------
__global__ void seed_mark_kernel(const int* __restrict__ users,
                                 const int* __restrict__ items,
                                 int* __restrict__ c1, int* __restrict__ c2,
                                 int* __restrict__ c3) {
    int t = blockIdx.x * blockDim.x + threadIdx.x;
    if (t >= 2 * BATCH) return;
    int node = (t < BATCH) ? users[t] : (N_USER + items[t - BATCH]);
    c3[node] = -2;
    c2[node] = -2;
    c1[node] = -2;
}

// edges into c3-marked nodes: mark their srcs as needed at levels 2 and 1
__global__ void markA_kernel(const int* __restrict__ esrc, const int* __restrict__ edst,
                             const float* __restrict__ veff,
                             const int* __restrict__ c3,
                             int* __restrict__ c2, int* __restrict__ c1) {
    int e = blockIdx.x * blockDim.x + threadIdx.x;
    if (e >= N_EDGES) return;
    if (c3[edst[e]] == -1) return;
    if (veff[e] == 0.0f) return;
    int s = esrc[e];
    c2[s] = -2;
    c1[s] = -2;
}

// edges into c2-marked nodes: mark their srcs as needed at level 1
__global__ void markB_kernel(const int* __restrict__ esrc, const int* __restrict__ edst,
                             const float* __restrict__ veff,
                             const int* __restrict__ c2, int* __restrict__ c1) {
    int e = blockIdx.x * blockDim.x + threadIdx.x;
    if (e >= N_EDGES) return;
    if (c2[edst[e]] == -1) return;
    if (veff[e] == 0.0f) return;
    c1[esrc[e]] = -2;
}

// ---------------------------------------------------------------------------
// Deterministic compact-index assignment via 3-kernel prefix scan over the
// contiguous c1|c2|c3 map array. Zero atomics. Rows pooled across levels.
// ---------------------------------------------------------------------------
__global__ void scan1_kernel(const int* __restrict__ cmaps, int* __restrict__ pre,
                             int* __restrict__ blockSums) {
    int b = blockIdx.x, t = threadIdx.x;
    int base = b * SCHUNK + t * 16;
    int v[16];
    int s = 0;
#pragma unroll
    for (int j = 0; j < 16; ++j) {
        int i = base + j;
        v[j] = (i < TOT3 && cmaps[i] == -2) ? 1 : 0;
        s += v[j];
    }
    int lane = t & 63, w = t >> 6;
    int x = s;
#pragma unroll
    for (int off = 1; off < 64; off <<= 1) {
        int y = __shfl_up(x, off, 64);
        if (lane >= off) x += y;
    }
    __shared__ int wsum[4];
    if (lane == 63) wsum[w] = x;
    __syncthreads();
    int woff = 0;
    for (int i = 0; i < w; ++i) woff += wsum[i];
    int run = woff + (x - s);  // exclusive prefix of this thread's first elem
#pragma unroll
    for (int j = 0; j < 16; ++j) {
        int i = base + j;
        if (i < TOT3) pre[i] = run;
        run += v[j];
    }
    if (t == 255) blockSums[b] = wsum[0] + wsum[1] + wsum[2] + wsum[3];
}

__global__ void scan2_kernel(int* __restrict__ blockSums) {
    __shared__ int sm[1024];
    int t = threadIdx.x;
    int v = (t < NBLK) ? blockSums[t] : 0;
    sm[t] = v;
    __syncthreads();
    for (int off = 1; off < 1024; off <<= 1) {
        int y = (t >= off) ? sm[t - off] : 0;
        __syncthreads();
        sm[t] += y;
        __syncthreads();
    }
    if (t < NBLK) blockSums[t] = sm[t] - v;  // exclusive
}

__global__ void scan3_kernel(int* __restrict__ cmaps, const int* __restrict__ pre,
                             const int* __restrict__ blockSums) {
    int i = blockIdx.x * blockDim.x + threadIdx.x;
    if (i >= TOT3) return;
    if (cmaps[i] == -2) {
        int r = pre[i] + blockSums[i / SCHUNK];
        cmaps[i] = (r < POOLROWS) ? r : -3;  // defensive; never hit at these sizes
    }
}

// ---------------------------------------------------------------------------
// Compact scatter-SpMMs: re-scan all edges, test membership, accumulate into
// the pre-zeroed pooled buffer. 16 threads/edge, float4 each. Distributed
// fp32 atomics only (L2-resident, degree ~1.2 -> negligible contention).
// ---------------------------------------------------------------------------
__global__ void comp_inputs_kernel(const float* __restrict__ src_user,
                                   const float* __restrict__ src_item,
                                   const int* __restrict__ c1,
                                   const int* __restrict__ esrc,
                                   const int* __restrict__ edst,
                                   const float* __restrict__ veff,
                                   float* __restrict__ pool) {
    int t = blockIdx.x * blockDim.x + threadIdx.x;
    int e = t >> 4;
    if (e >= N_EDGES) return;
    int dr = c1[edst[e]];
    if (dr < 0) return;
    float v = veff[e];
    if (v == 0.0f) return;
    int c = (t & 15) << 2;
    int s = esrc[e];
    const float* srow = (s < N_USER) ? (src_user + (size_t)s * DIM)
                                     : (src_item + (size_t)(s - N_USER) * DIM);
    float4 x = *(const float4*)(srow + c);
    float* drow = pool + (size_t)dr * DIM + c;
    atomicAdd(drow + 0, v * x.x);
    atomicAdd(drow + 1, v * x.y);
    atomicAdd(drow + 2, v * x.z);
    atomicAdd(drow + 3, v * x.w);
}

// src rows come from the (final) previous-level pooled rows; row spaces of
// different levels are disjoint by construction of the global prefix scan.
__global__ void comp_level_kernel(const int* __restrict__ cs,   // src-level map
                                  const int* __restrict__ cd,   // dst-level map
                                  const int* __restrict__ esrc,
                                  const int* __restrict__ edst,
                                  const float* __restrict__ veff,
                                  float* __restrict__ pool) {
    int t = blockIdx.x * blockDim.x + threadIdx.x;
    int e = t >> 4;
    if (e >= N_EDGES) return;
    int dr = cd[edst[e]];
    if (dr < 0) return;
    float v = veff[e];
    if (v == 0.0f) return;
    int sr = cs[esrc[e]];
    if (sr < 0) return;  // defensive; marking guarantees sr >= 0
    int c = (t & 15) << 2;
    float4 x = *(const float4*)(pool + (size_t)sr * DIM + c);
    float* drow = pool + (size_t)dr * DIM + c;
    atomicAdd(drow + 0, v * x.x);
    atomicAdd(drow + 1, v * x.y);
    atomicAdd(drow + 2, v * x.z);
    atomicAdd(drow + 3, v * x.w);
}

// ---------------------------------------------------------------------------
// Fused extraction + pooling + ratings. One 64-lane wave per batch element.
// ---------------------------------------------------------------------------
__global__ void out_fused_kernel(const float* __restrict__ user_emb,
                                 const float* __restrict__ item_emb,
                                 const int* __restrict__ users,
                                 const int* __restrict__ items,
                                 const int* __restrict__ c1, const int* __restrict__ c2,
                                 const int* __restrict__ c3,
                                 const float* __restrict__ pool,
                                 float* __restrict__ ratings,
                                 float* __restrict__ inter,
                                 float* __restrict__ inter_layers) {
    int b = blockIdx.x * 4 + (threadIdx.x >> 6);
    int d = threadIdx.x & 63;
    if (b >= BATCH) return;
    int un = users[b];
    int in_node = N_USER + items[b];

    // sampled nodes are seeded+assigned; max() is a no-cost safety clamp
    int r1u = max(c1[un], 0), r1i = max(c1[in_node], 0);
    int r2u = max(c2[un], 0), r2i = max(c2[in_node], 0);
    int r3u = max(c3[un], 0), r3i = max(c3[in_node], 0);

    float u0 = user_emb[(size_t)un * DIM + d];
    float i0 = item_emb[(size_t)items[b] * DIM + d];
    float u1 = pool[(size_t)r1u * DIM + d];
    float i1 = pool[(size_t)r1i * DIM + d];
    float u2 = pool[(size_t)r2u * DIM + d];
    float i2 = pool[(size_t)r2i * DIM + d];
    float u3 = pool[(size_t)r3u * DIM + d];
    float i3 = pool[(size_t)r3i * DIM + d];

    size_t base = (size_t)b * 4 * DIM + d;
    inter_layers[base + 0 * DIM] = u0 * i0;
    inter_layers[base + 1 * DIM] = u1 * i1;
    inter_layers[base + 2 * DIM] = u2 * i2;
    inter_layers[base + 3 * DIM] = u3 * i3;

    float lu = (u0 + u1 + u2 + u3) * 0.25f;
    float li = (i0 + i1 + i2 + i3) * 0.25f;
    float p = lu * li;
    inter[(size_t)b * DIM + d] = p;
    float s = p;
#pragma unroll
    for (int off = 32; off > 0; off >>= 1) s += __shfl_down(s, off, 64);
    if (d == 0) ratings[b] = 1.0f / (1.0f + expf(-s));
}

// ---------------------------------------------------------------------------
extern "C" void kernel_launch(void* const* d_in, const int* in_sizes, int n_in,
                              void* d_out, int out_size, void* d_ws, size_t ws_size,
                              hipStream_t stream) {
    const float* user_emb  = (const float*)d_in[0];
    const float* item_emb  = (const float*)d_in[1];
    const float* edge_vals = (const float*)d_in[2];
    const int*   edge_src  = (const int*)d_in[3];
    const int*   edge_dst  = (const int*)d_in[4];
    const int*   users     = (const int*)d_in[5];
    const int*   items     = (const int*)d_in[6];

    float* out          = (float*)d_out;
    float* ratings      = out;                       // [BATCH]
    float* inter        = out + BATCH;               // [BATCH, DIM]
    float* inter_layers = out + BATCH + BATCH * DIM; // [BATCH, 4, DIM]

    char* ws = (char*)d_ws;
    size_t off = 0;
    int* c1 = (int*)(ws + off); off += (size_t)N_NODES * sizeof(int);
    int* c2 = (int*)(ws + off); off += (size_t)N_NODES * sizeof(int);
    int* c3 = (int*)(ws + off); off += (size_t)N_NODES * sizeof(int);
    float* pool = (float*)(ws + off); off += (size_t)POOLROWS * DIM * sizeof(float);
    float* veff = (float*)(ws + off); off += (size_t)N_EDGES * sizeof(float);
    int* pre = (int*)(ws + off); off += (size_t)TOT3 * sizeof(int);
    int* blockSums = (int*)(ws + off); off += 1024 * sizeof(int);

    const dim3 blk(256);
    const dim3 egrid((N_EDGES + 255) / 256);
    const dim3 e16grid((N_EDGES * 16 + 255) / 256);

    // bulk init: maps -1 (c1..c3 contiguous), pooled rows 0
    hipMemsetAsync(c1, 0xFF, (size_t)TOT3 * sizeof(int), stream);
    hipMemsetAsync(pool, 0, (size_t)POOLROWS * DIM * sizeof(float), stream);

    veff_kernel<<<egrid, blk, 0, stream>>>(edge_vals, veff);

    seed_mark_kernel<<<(2 * BATCH + 255) / 256, blk, 0, stream>>>(
        users, items, c1, c2, c3);

    markA_kernel<<<egrid, blk, 0, stream>>>(edge_src, edge_dst, veff, c3, c2, c1);
    markB_kernel<<<egrid, blk, 0, stream>>>(edge_src, edge_dst, veff, c2, c1);

    scan1_kernel<<<NBLK, blk, 0, stream>>>(c1, pre, blockSums);
    scan2_kernel<<<1, 1024, 0, stream>>>(blockSums);
    scan3_kernel<<<(TOT3 + 255) / 256, blk, 0, stream>>>(c1, pre, blockSums);

    comp_inputs_kernel<<<e16grid, blk, 0, stream>>>(
        user_emb, item_emb, c1, edge_src, edge_dst, veff, pool);
    comp_level_kernel<<<e16grid, blk, 0, stream>>>(
        c1, c2, edge_src, edge_dst, veff, pool);
    comp_level_kernel<<<e16grid, blk, 0, stream>>>(
        c2, c3, edge_src, edge_dst, veff, pool);

    out_fused_kernel<<<BATCH / 4, blk, 0, stream>>>(
        user_emb, item_emb, users, items, c1, c2, c3, pool,
        ratings, inter, inter_layers);
}

// Round 7
// 200.909 us; speedup vs baseline: 5.3648x; 1.0215x over previous
//
#include <hip/hip_runtime.h>

#define N_USER   300000
#define M_ITEM   700000
#define N_NODES  (N_USER + M_ITEM)
#define DIM      64
#define N_EDGES  1200000
#define BATCH    4096

#define POOLROWS 131072                 // pooled compact rows across all 3 levels (need ~66K)
#define TOT3     (3 * N_NODES)          // 3,000,000 map entries
#define SCHUNK   4096                   // entries per scan block (256 thr x 16)
#define NBLK     ((TOT3 + SCHUNK - 1) / SCHUNK)  // 733

// ---------------------------------------------------------------------------
// Threefry2x32-20, JAX partitionable path (bit-exact, verified round 2):
// per element e: x0 = 0 + k0, x1 = e + k1; 20 rounds; bits = x0^x1.
// Inlined into consumers; evaluated only for edges that pass membership.
// ---------------------------------------------------------------------------
__device__ __forceinline__ unsigned rotl32(unsigned x, int r) {
    return (x << r) | (x >> (32 - r));
}

__device__ __forceinline__ float edge_veff(int e, const float* __restrict__ evals) {
    unsigned ks[3] = {0u, 42u, 0u ^ 42u ^ 0x1BD11BDAu};
    unsigned x0 = ks[0];
    unsigned x1 = (unsigned)e + ks[1];
    const int rotA[4] = {13, 15, 26, 6};
    const int rotB[4] = {17, 29, 16, 24};
#pragma unroll
    for (int g = 0; g < 5; ++g) {
#pragma unroll
        for (int j = 0; j < 4; ++j) {
            int r = (g & 1) ? rotB[j] : rotA[j];
            x0 += x1;
            x1 = rotl32(x1, r);
            x1 ^= x0;
        }
        x0 += ks[(g + 1) % 3];
        x1 += ks[(g + 2) % 3] + (unsigned)(g + 1);
    }
    unsigned bits = x0 ^ x1;
    float u = __uint_as_float((bits >> 9) | 0x3F800000u) - 1.0f;
    return (u >= 0.1f) ? evals[e] * (1.0f / 0.9f) : 0.0f;
}

// ---------------------------------------------------------------------------
// Fast init: maps -1 (int4) + pool 0 (float4), grid-stride, full-occupancy.
// Replaces hipMemsetAsync's ~100us low-occupancy fillBufferAligned.
// ---------------------------------------------------------------------------
__global__ void fill_init_kernel(int4* __restrict__ maps4, float4* __restrict__ pool4) {
    const int MAP4  = TOT3 / 4;            // 750,000
    const int POOL4 = POOLROWS * (DIM / 4); // 2,097,152
    int tid = blockIdx.x * blockDim.x + threadIdx.x;
    int stride = gridDim.x * blockDim.x;
    int4 m1 = make_int4(-1, -1, -1, -1);
    float4 z = {0.f, 0.f, 0.f, 0.f};
    for (int i = tid; i < MAP4; i += stride) maps4[i] = m1;
    for (int i = tid; i < POOL4; i += stride) pool4[i] = z;
}

// ---------------------------------------------------------------------------
// Marking: idempotent plain stores of -2 only. No atomics, no lists.
// ---------------------------------------------------------------------------
__global__ void seed_mark_kernel(const int* __restrict__ users,
                                 const int* __restrict__ items,
                                 int* __restrict__ c1, int* __restrict__ c2,
                                 int* __restrict__ c3) {
    int t = blockIdx.x * blockDim.x + threadIdx.x;
    if (t >= 2 * BATCH) return;
    int node = (t < BATCH) ? users[t] : (N_USER + items[t - BATCH]);
    c3[node] = -2;
    c2[node] = -2;
    c1[node] = -2;
}

// edges into c3-marked nodes: mark their srcs as needed at levels 2 and 1
__global__ void markA_kernel(const int* __restrict__ esrc, const int* __restrict__ edst,
                             const float* __restrict__ evals,
                             const int* __restrict__ c3,
                             int* __restrict__ c2, int* __restrict__ c1) {
    int e = blockIdx.x * blockDim.x + threadIdx.x;
    if (e >= N_EDGES) return;
    if (c3[edst[e]] == -1) return;
    if (edge_veff(e, evals) == 0.0f) return;
    int s = esrc[e];
    c2[s] = -2;
    c1[s] = -2;
}

// edges into c2-marked nodes: mark their srcs as needed at level 1
__global__ void markB_kernel(const int* __restrict__ esrc, const int* __restrict__ edst,
                             const float* __restrict__ evals,
                             const int* __restrict__ c2, int* __restrict__ c1) {
    int e = blockIdx.x * blockDim.x + threadIdx.x;
    if (e >= N_EDGES) return;
    if (c2[edst[e]] == -1) return;
    if (edge_veff(e, evals) == 0.0f) return;
    c1[esrc[e]] = -2;
}

// ---------------------------------------------------------------------------
// Deterministic compact-index assignment via 3-kernel prefix scan over the
// contiguous c1|c2|c3 map array. Zero atomics. Rows pooled across levels.
// ---------------------------------------------------------------------------
__global__ void scan1_kernel(const int* __restrict__ cmaps, int* __restrict__ pre,
                             int* __restrict__ blockSums) {
    int b = blockIdx.x, t = threadIdx.x;
    int base = b * SCHUNK + t * 16;
    int v[16];
    int s = 0;
#pragma unroll
    for (int j = 0; j < 16; ++j) {
        int i = base + j;
        v[j] = (i < TOT3 && cmaps[i] == -2) ? 1 : 0;
        s += v[j];
    }
    int lane = t & 63, w = t >> 6;
    int x = s;
#pragma unroll
    for (int off = 1; off < 64; off <<= 1) {
        int y = __shfl_up(x, off, 64);
        if (lane >= off) x += y;
    }
    __shared__ int wsum[4];
    if (lane == 63) wsum[w] = x;
    __syncthreads();
    int woff = 0;
    for (int i = 0; i < w; ++i) woff += wsum[i];
    int run = woff + (x - s);  // exclusive prefix of this thread's first elem
#pragma unroll
    for (int j = 0; j < 16; ++j) {
        int i = base + j;
        if (i < TOT3) pre[i] = run;
        run += v[j];
    }
    if (t == 255) blockSums[b] = wsum[0] + wsum[1] + wsum[2] + wsum[3];
}

__global__ void scan2_kernel(int* __restrict__ blockSums) {
    __shared__ int sm[1024];
    int t = threadIdx.x;
    int v = (t < NBLK) ? blockSums[t] : 0;
    sm[t] = v;
    __syncthreads();
    for (int off = 1; off < 1024; off <<= 1) {
        int y = (t >= off) ? sm[t - off] : 0;
        __syncthreads();
        sm[t] += y;
        __syncthreads();
    }
    if (t < NBLK) blockSums[t] = sm[t] - v;  // exclusive
}

__global__ void scan3_kernel(int* __restrict__ cmaps, const int* __restrict__ pre,
                             const int* __restrict__ blockSums) {
    int i = blockIdx.x * blockDim.x + threadIdx.x;
    if (i >= TOT3) return;
    if (cmaps[i] == -2) {
        int r = pre[i] + blockSums[i / SCHUNK];
        cmaps[i] = (r < POOLROWS) ? r : -3;  // defensive; never hit at these sizes
    }
}

// ---------------------------------------------------------------------------
// Compact scatter-SpMMs: re-scan all edges, test membership, accumulate into
// the pre-zeroed pooled buffer. 16 threads/edge, float4 each. Distributed
// fp32 atomics only (L2-resident, degree ~1.2 -> negligible contention).
// ---------------------------------------------------------------------------
__global__ void comp_inputs_kernel(const float* __restrict__ src_user,
                                   const float* __restrict__ src_item,
                                   const int* __restrict__ c1,
                                   const int* __restrict__ esrc,
                                   const int* __restrict__ edst,
                                   const float* __restrict__ evals,
                                   float* __restrict__ pool) {
    int t = blockIdx.x * blockDim.x + threadIdx.x;
    int e = t >> 4;
    if (e >= N_EDGES) return;
    int dr = c1[edst[e]];
    if (dr < 0) return;
    float v = edge_veff(e, evals);
    if (v == 0.0f) return;
    int c = (t & 15) << 2;
    int s = esrc[e];
    const float* srow = (s < N_USER) ? (src_user + (size_t)s * DIM)
                                     : (src_item + (size_t)(s - N_USER) * DIM);
    float4 x = *(const float4*)(srow + c);
    float* drow = pool + (size_t)dr * DIM + c;
    atomicAdd(drow + 0, v * x.x);
    atomicAdd(drow + 1, v * x.y);
    atomicAdd(drow + 2, v * x.z);
    atomicAdd(drow + 3, v * x.w);
}

// src rows come from the (final) previous-level pooled rows; row spaces of
// different levels are disjoint by construction of the global prefix scan.
__global__ void comp_level_kernel(const int* __restrict__ cs,   // src-level map
                                  const int* __restrict__ cd,   // dst-level map
                                  const int* __restrict__ esrc,
                                  const int* __restrict__ edst,
                                  const float* __restrict__ evals,
                                  float* __restrict__ pool) {
    int t = blockIdx.x * blockDim.x + threadIdx.x;
    int e = t >> 4;
    if (e >= N_EDGES) return;
    int dr = cd[edst[e]];
    if (dr < 0) return;
    float v = edge_veff(e, evals);
    if (v == 0.0f) return;
    int sr = cs[esrc[e]];
    if (sr < 0) return;  // defensive; marking guarantees sr >= 0
    int c = (t & 15) << 2;
    float4 x = *(const float4*)(pool + (size_t)sr * DIM + c);
    float* drow = pool + (size_t)dr * DIM + c;
    atomicAdd(drow + 0, v * x.x);
    atomicAdd(drow + 1, v * x.y);
    atomicAdd(drow + 2, v * x.z);
    atomicAdd(drow + 3, v * x.w);
}

// ---------------------------------------------------------------------------
// Fused extraction + pooling + ratings. One 64-lane wave per batch element.
// ---------------------------------------------------------------------------
__global__ void out_fused_kernel(const float* __restrict__ user_emb,
                                 const float* __restrict__ item_emb,
                                 const int* __restrict__ users,
                                 const int* __restrict__ items,
                                 const int* __restrict__ c1, const int* __restrict__ c2,
                                 const int* __restrict__ c3,
                                 const float* __restrict__ pool,
                                 float* __restrict__ ratings,
                                 float* __restrict__ inter,
                                 float* __restrict__ inter_layers) {
    int b = blockIdx.x * 4 + (threadIdx.x >> 6);
    int d = threadIdx.x & 63;
    if (b >= BATCH) return;
    int un = users[b];
    int in_node = N_USER + items[b];

    // sampled nodes are seeded+assigned; max() is a no-cost safety clamp
    int r1u = max(c1[un], 0), r1i = max(c1[in_node], 0);
    int r2u = max(c2[un], 0), r2i = max(c2[in_node], 0);
    int r3u = max(c3[un], 0), r3i = max(c3[in_node], 0);

    float u0 = user_emb[(size_t)un * DIM + d];
    float i0 = item_emb[(size_t)items[b] * DIM + d];
    float u1 = pool[(size_t)r1u * DIM + d];
    float i1 = pool[(size_t)r1i * DIM + d];
    float u2 = pool[(size_t)r2u * DIM + d];
    float i2 = pool[(size_t)r2i * DIM + d];
    float u3 = pool[(size_t)r3u * DIM + d];
    float i3 = pool[(size_t)r3i * DIM + d];

    size_t base = (size_t)b * 4 * DIM + d;
    inter_layers[base + 0 * DIM] = u0 * i0;
    inter_layers[base + 1 * DIM] = u1 * i1;
    inter_layers[base + 2 * DIM] = u2 * i2;
    inter_layers[base + 3 * DIM] = u3 * i3;

    float lu = (u0 + u1 + u2 + u3) * 0.25f;
    float li = (i0 + i1 + i2 + i3) * 0.25f;
    float p = lu * li;
    inter[(size_t)b * DIM + d] = p;
    float s = p;
#pragma unroll
    for (int off = 32; off > 0; off >>= 1) s += __shfl_down(s, off, 64);
    if (d == 0) ratings[b] = 1.0f / (1.0f + expf(-s));
}

// ---------------------------------------------------------------------------
extern "C" void kernel_launch(void* const* d_in, const int* in_sizes, int n_in,
                              void* d_out, int out_size, void* d_ws, size_t ws_size,
                              hipStream_t stream) {
    const float* user_emb  = (const float*)d_in[0];
    const float* item_emb  = (const float*)d_in[1];
    const float* edge_vals = (const float*)d_in[2];
    const int*   edge_src  = (const int*)d_in[3];
    const int*   edge_dst  = (const int*)d_in[4];
    const int*   users     = (const int*)d_in[5];
    const int*   items     = (const int*)d_in[6];

    float* out          = (float*)d_out;
    float* ratings      = out;                       // [BATCH]
    float* inter        = out + BATCH;               // [BATCH, DIM]
    float* inter_layers = out + BATCH + BATCH * DIM; // [BATCH, 4, DIM]

    char* ws = (char*)d_ws;
    size_t off = 0;
    int* c1 = (int*)(ws + off); off += (size_t)N_NODES * sizeof(int);
    int* c2 = (int*)(ws + off); off += (size_t)N_NODES * sizeof(int);
    int* c3 = (int*)(ws + off); off += (size_t)N_NODES * sizeof(int);
    float* pool = (float*)(ws + off); off += (size_t)POOLROWS * DIM * sizeof(float);
    int* pre = (int*)(ws + off); off += (size_t)TOT3 * sizeof(int);
    int* blockSums = (int*)(ws + off); off += 1024 * sizeof(int);

    const dim3 blk(256);
    const dim3 egrid((N_EDGES + 255) / 256);
    const dim3 e16grid((N_EDGES * 16 + 255) / 256);

    // full-occupancy init of maps (-1) and pool (0); c1..c3 contiguous
    fill_init_kernel<<<2048, blk, 0, stream>>>((int4*)c1, (float4*)pool);

    seed_mark_kernel<<<(2 * BATCH + 255) / 256, blk, 0, stream>>>(
        users, items, c1, c2, c3);

    markA_kernel<<<egrid, blk, 0, stream>>>(edge_src, edge_dst, edge_vals, c3, c2, c1);
    markB_kernel<<<egrid, blk, 0, stream>>>(edge_src, edge_dst, edge_vals, c2, c1);

    scan1_kernel<<<NBLK, blk, 0, stream>>>(c1, pre, blockSums);
    scan2_kernel<<<1, 1024, 0, stream>>>(blockSums);
    scan3_kernel<<<(TOT3 + 255) / 256, blk, 0, stream>>>(c1, pre, blockSums);

    comp_inputs_kernel<<<e16grid, blk, 0, stream>>>(
        user_emb, item_emb, c1, edge_src, edge_dst, edge_vals, pool);
    comp_level_kernel<<<e16grid, blk, 0, stream>>>(
        c1, c2, edge_src, edge_dst, edge_vals, pool);
    comp_level_kernel<<<e16grid, blk, 0, stream>>>(
        c2, c3, edge_src, edge_dst, edge_vals, pool);

    out_fused_kernel<<<BATCH / 4, blk, 0, stream>>>(
        user_emb, item_emb, users, items, c1, c2, c3, pool,
        ratings, inter, inter_layers);
}

// Round 8
// 183.831 us; speedup vs baseline: 5.8632x; 1.0929x over previous
//
#include <hip/hip_runtime.h>

#define N_USER   300000
#define M_ITEM   700000
#define N_NODES  (N_USER + M_ITEM)
#define DIM      64
#define N_EDGES  1200000
#define BATCH    4096

#define POOLROWS 131072                 // pooled compact rows (need ~60K)
#define TOT3     (3 * N_NODES)          // 3,000,000 map entries
#define SCHUNK   4096                   // entries per scan block (256 thr x 16)
#define NBLK_M   ((TOT3 + SCHUNK - 1) / SCHUNK)     // 733 map-count blocks
#define NBLK_E   ((N_EDGES + SCHUNK - 1) / SCHUNK)  // 293 edge-count blocks
#define CAPE     262144                 // compact edge entries (need ~65K)

// ---------------------------------------------------------------------------
// Threefry2x32-20, JAX partitionable path (bit-exact, verified round 2).
// ---------------------------------------------------------------------------
__device__ __forceinline__ unsigned rotl32(unsigned x, int r) {
    return (x << r) | (x >> (32 - r));
}

__device__ __forceinline__ float edge_veff(int e, const float* __restrict__ evals) {
    unsigned ks[3] = {0u, 42u, 0u ^ 42u ^ 0x1BD11BDAu};
    unsigned x0 = ks[0];
    unsigned x1 = (unsigned)e + ks[1];
    const int rotA[4] = {13, 15, 26, 6};
    const int rotB[4] = {17, 29, 16, 24};
#pragma unroll
    for (int g = 0; g < 5; ++g) {
#pragma unroll
        for (int j = 0; j < 4; ++j) {
            int r = (g & 1) ? rotB[j] : rotA[j];
            x0 += x1;
            x1 = rotl32(x1, r);
            x1 ^= x0;
        }
        x0 += ks[(g + 1) % 3];
        x1 += ks[(g + 2) % 3] + (unsigned)(g + 1);
    }
    unsigned bits = x0 ^ x1;
    float u = __uint_as_float((bits >> 9) | 0x3F800000u) - 1.0f;
    return (u >= 0.1f) ? evals[e] * (1.0f / 0.9f) : 0.0f;
}

// ---------------------------------------------------------------------------
// Fast init: maps -1 (int4) + pool 0 (float4), grid-stride, full-occupancy.
// ---------------------------------------------------------------------------
__global__ void fill_init_kernel(int4* __restrict__ maps4, float4* __restrict__ pool4) {
    const int MAP4  = TOT3 / 4;             // 750,000
    const int POOL4 = POOLROWS * (DIM / 4); // 2,097,152
    int tid = blockIdx.x * blockDim.x + threadIdx.x;
    int stride = gridDim.x * blockDim.x;
    int4 m1 = make_int4(-1, -1, -1, -1);
    float4 z = {0.f, 0.f, 0.f, 0.f};
    for (int i = tid; i < MAP4; i += stride) maps4[i] = m1;
    for (int i = tid; i < POOL4; i += stride) pool4[i] = z;
}

// ---------------------------------------------------------------------------
// Marking: idempotent plain stores of -2 only.
// ---------------------------------------------------------------------------
__global__ void seed_mark_kernel(const int* __restrict__ users,
                                 const int* __restrict__ items,
                                 int* __restrict__ c1, int* __restrict__ c2,
                                 int* __restrict__ c3) {
    int t = blockIdx.x * blockDim.x + threadIdx.x;
    if (t >= 2 * BATCH) return;
    int node = (t < BATCH) ? users[t] : (N_USER + items[t - BATCH]);
    c3[node] = -2;
    c2[node] = -2;
    c1[node] = -2;
}

__global__ void markA_kernel(const int* __restrict__ esrc, const int* __restrict__ edst,
                             const float* __restrict__ evals,
                             const int* __restrict__ c3,
                             int* __restrict__ c2, int* __restrict__ c1) {
    int e = blockIdx.x * blockDim.x + threadIdx.x;
    if (e >= N_EDGES) return;
    if (c3[edst[e]] == -1) return;
    if (edge_veff(e, evals) == 0.0f) return;
    int s = esrc[e];
    c2[s] = -2;
    c1[s] = -2;
}

__global__ void markB_kernel(const int* __restrict__ esrc, const int* __restrict__ edst,
                             const float* __restrict__ evals,
                             const int* __restrict__ c2, int* __restrict__ c1) {
    int e = blockIdx.x * blockDim.x + threadIdx.x;
    if (e >= N_EDGES) return;
    if (c2[edst[e]] == -1) return;
    if (edge_veff(e, evals) == 0.0f) return;
    c1[esrc[e]] = -2;
}

// ---------------------------------------------------------------------------
// Fused count pass: blocks [0,733) count marked map entries per 4096-chunk;
// blocks [733,1026) count edge classes {3,2,1} per 4096-edge chunk.
// Class m(e) = highest level containing dst(e); nesting c3<=c2<=c1 holds by
// construction (seeds in all; markA srcs in c2,c1; markB srcs in c1).
// ---------------------------------------------------------------------------
__global__ void count_kernel(const int* __restrict__ cmaps,
                             const int* __restrict__ edst,
                             const float* __restrict__ evals,
                             const int* __restrict__ c1, const int* __restrict__ c2,
                             const int* __restrict__ c3,
                             int* __restrict__ mapCnt, int4* __restrict__ edgeCnt) {
    int b = blockIdx.x, t = threadIdx.x;
    int lane = t & 63, w = t >> 6;
    if (b < NBLK_M) {
        int base = b * SCHUNK + t * 16;
        int s = 0;
#pragma unroll
        for (int j = 0; j < 16; ++j) {
            int i = base + j;
            s += (i < TOT3 && cmaps[i] == -2) ? 1 : 0;
        }
#pragma unroll
        for (int off = 32; off; off >>= 1) s += __shfl_down(s, off, 64);
        __shared__ int ws[4];
        if (lane == 0) ws[w] = s;
        __syncthreads();
        if (t == 0) mapCnt[b] = ws[0] + ws[1] + ws[2] + ws[3];
    } else {
        int base = (b - NBLK_M) * SCHUNK + t * 16;
        int s3 = 0, s2 = 0, s1 = 0;
#pragma unroll
        for (int j = 0; j < 16; ++j) {
            int e = base + j;
            if (e >= N_EDGES) continue;
            int d = edst[e];
            if (c1[d] == -1) continue;               // not in any level
            if (edge_veff(e, evals) == 0.0f) continue;
            if (c3[d] != -1) s3++;
            else if (c2[d] != -1) s2++;
            else s1++;
        }
        int p = (s3 << 16) | s2;                      // block sums <= 4096: no carry
#pragma unroll
        for (int off = 32; off; off >>= 1) {
            p  += __shfl_down(p, off, 64);
            s1 += __shfl_down(s1, off, 64);
        }
        __shared__ int wp[4], w1[4];
        if (lane == 0) { wp[w] = p; w1[w] = s1; }
        __syncthreads();
        if (t == 0) {
            int P = wp[0] + wp[1] + wp[2] + wp[3];
            int S1 = w1[0] + w1[1] + w1[2] + w1[3];
            edgeCnt[b - NBLK_M] = make_int4(P >> 16, P & 0xFFFF, S1, 0);
        }
    }
}

// ---------------------------------------------------------------------------
// Single-block offsets: exclusive scans of mapCnt (rows) and edgeCnt (3
// classes, grouped class-3 first, then 2, then 1). cuts = (n3, n3+n2, total).
// ---------------------------------------------------------------------------
__global__ void offsets_kernel(int* __restrict__ mapCnt, int4* __restrict__ edgeCnt,
                               int4* __restrict__ cuts) {
    __shared__ int sm[1024];
    int t = threadIdx.x;

    int v = (t < NBLK_M) ? mapCnt[t] : 0;
    sm[t] = v; __syncthreads();
    for (int off = 1; off < 1024; off <<= 1) {
        int y = (t >= off) ? sm[t - off] : 0;
        __syncthreads(); sm[t] += y; __syncthreads();
    }
    if (t < NBLK_M) mapCnt[t] = sm[t] - v;  // exclusive row base per map block
    __syncthreads();

    int4 ev = (t < NBLK_E) ? edgeCnt[t] : make_int4(0, 0, 0, 0);
    sm[t] = ev.x; __syncthreads();
    for (int off = 1; off < 1024; off <<= 1) {
        int y = (t >= off) ? sm[t - off] : 0;
        __syncthreads(); sm[t] += y; __syncthreads();
    }
    int px = sm[t] - ev.x; int t3 = sm[1023]; __syncthreads();

    sm[t] = ev.y; __syncthreads();
    for (int off = 1; off < 1024; off <<= 1) {
        int y = (t >= off) ? sm[t - off] : 0;
        __syncthreads(); sm[t] += y; __syncthreads();
    }
    int py = sm[t] - ev.y; int t2 = sm[1023]; __syncthreads();

    sm[t] = ev.z; __syncthreads();
    for (int off = 1; off < 1024; off <<= 1) {
        int y = (t >= off) ? sm[t - off] : 0;
        __syncthreads(); sm[t] += y; __syncthreads();
    }
    int pz = sm[t] - ev.z; int t1 = sm[1023];

    if (t < NBLK_E) edgeCnt[t] = make_int4(px, t3 + py, t3 + t2 + pz, 0);
    if (t == 0) *cuts = make_int4(t3, t3 + t2, t3 + t2 + t1, 0);
}

// ---------------------------------------------------------------------------
// Fused assign + scatter: map blocks turn -2 into pooled row indices (rank
// recomputed locally — no pre[] array); edge blocks write the class-grouped
// compact edge list (src, dst, veff). Membership test `!= -1` is invariant
// under the concurrent -2 -> rowidx transition, so the fusion is race-safe.
// ---------------------------------------------------------------------------
__global__ void assign_scatter_kernel(int* __restrict__ cmaps,
                                      const int* __restrict__ mapOff,
                                      const int4* __restrict__ edgeOff,
                                      const int* __restrict__ esrc,
                                      const int* __restrict__ edst,
                                      const float* __restrict__ evals,
                                      const int* __restrict__ c1,
                                      const int* __restrict__ c2,
                                      const int* __restrict__ c3,
                                      int* __restrict__ el_src,
                                      int* __restrict__ el_dst,
                                      float* __restrict__ el_v) {
    int b = blockIdx.x, t = threadIdx.x;
    int lane = t & 63, w = t >> 6;
    if (b < NBLK_M) {
        int base = b * SCHUNK + t * 16;
        int v[16]; int s = 0;
#pragma unroll
        for (int j = 0; j < 16; ++j) {
            int i = base + j;
            v[j] = (i < TOT3 && cmaps[i] == -2) ? 1 : 0;
            s += v[j];
        }
        int x = s;
#pragma unroll
        for (int off = 1; off < 64; off <<= 1) {
            int y = __shfl_up(x, off, 64);
            if (lane >= off) x += y;
        }
        __shared__ int ws[4];
        if (lane == 63) ws[w] = x;
        __syncthreads();
        int woff = 0;
        for (int i = 0; i < w; ++i) woff += ws[i];
        int run = mapOff[b] + woff + (x - s);
#pragma unroll
        for (int j = 0; j < 16; ++j) {
            int i = base + j;
            if (v[j]) { cmaps[i] = (run < POOLROWS) ? run : -3; run++; }
        }
    } else {
        int base = (b - NBLK_M) * SCHUNK + t * 16;
        int m[16]; float vv[16];
        int s3 = 0, s2 = 0, s1 = 0;
#pragma unroll
        for (int j = 0; j < 16; ++j) {
            int e = base + j;
            m[j] = 0; vv[j] = 0.f;
            if (e >= N_EDGES) continue;
            int d = edst[e];
            if (c1[d] == -1) continue;
            float vf = edge_veff(e, evals);
            if (vf == 0.0f) continue;
            vv[j] = vf;
            if (c3[d] != -1)      { m[j] = 3; s3++; }
            else if (c2[d] != -1) { m[j] = 2; s2++; }
            else                  { m[j] = 1; s1++; }
        }
        int p = (s3 << 16) | s2;  // block-local sums <= 4096: fields never carry
        int x = p, x1 = s1;
#pragma unroll
        for (int off = 1; off < 64; off <<= 1) {
            int y = __shfl_up(x, off, 64);
            int y1 = __shfl_up(x1, off, 64);
            if (lane >= off) { x += y; x1 += y1; }
        }
        __shared__ int wp[4], w1s[4];
        if (lane == 63) { wp[w] = x; w1s[w] = x1; }
        __syncthreads();
        int wo = 0, wo1 = 0;
        for (int i = 0; i < w; ++i) { wo += wp[i]; wo1 += w1s[i]; }
        int ex = wo + (x - p);
        int r3 = ex >> 16, r2 = ex & 0xFFFF, r1 = wo1 + (x1 - s1);
        int4 eo = edgeOff[b - NBLK_M];
#pragma unroll
        for (int j = 0; j < 16; ++j) {
            if (!m[j]) continue;
            int e = base + j, pos;
            if (m[j] == 3)      pos = eo.x + r3++;
            else if (m[j] == 2) pos = eo.y + r2++;
            else                pos = eo.z + r1++;
            el_src[pos] = esrc[e];
            el_dst[pos] = edst[e];
            el_v[pos]   = vv[j];
        }
    }
}

// ---------------------------------------------------------------------------
// Compact scatter-SpMMs over the class-grouped list. Level-1 uses all
// entries [0, cuts.z); level-2 [0, cuts.y); level-3 [0, cuts.x).
// Grid-stride with dynamic ne read on device (graph-capture safe).
// ---------------------------------------------------------------------------
__global__ void comp1_kernel(const float* __restrict__ src_user,
                             const float* __restrict__ src_item,
                             const int* __restrict__ c1,
                             const int* __restrict__ el_src,
                             const int* __restrict__ el_dst,
                             const float* __restrict__ el_v,
                             const int4* __restrict__ cuts,
                             float* __restrict__ pool) {
    int total = min(cuts->z, CAPE) * 16;
    int stride = gridDim.x * blockDim.x;
    for (int t = blockIdx.x * blockDim.x + threadIdx.x; t < total; t += stride) {
        int e = t >> 4, c = (t & 15) << 2;
        int s = el_src[e];
        int dr = c1[el_dst[e]];
        if (dr < 0) continue;
        float v = el_v[e];
        const float* srow = (s < N_USER) ? (src_user + (size_t)s * DIM)
                                         : (src_item + (size_t)(s - N_USER) * DIM);
        float4 x = *(const float4*)(srow + c);
        float* drow = pool + (size_t)dr * DIM + c;
        atomicAdd(drow + 0, v * x.x);
        atomicAdd(drow + 1, v * x.y);
        atomicAdd(drow + 2, v * x.z);
        atomicAdd(drow + 3, v * x.w);
    }
}

__global__ void comp_level_kernel(const int* __restrict__ cs,  // src-level map
                                  const int* __restrict__ cd,  // dst-level map
                                  const int* __restrict__ el_src,
                                  const int* __restrict__ el_dst,
                                  const float* __restrict__ el_v,
                                  const int4* __restrict__ cuts, int which,
                                  float* __restrict__ pool) {
    int ne = (which == 2) ? cuts->y : cuts->x;
    int total = min(ne, CAPE) * 16;
    int stride = gridDim.x * blockDim.x;
    for (int t = blockIdx.x * blockDim.x + threadIdx.x; t < total; t += stride) {
        int e = t >> 4, c = (t & 15) << 2;
        int sr = cs[el_src[e]];
        int dr = cd[el_dst[e]];
        if (sr < 0 || dr < 0) continue;
        float v = el_v[e];
        float4 x = *(const float4*)(pool + (size_t)sr * DIM + c);
        float* drow = pool + (size_t)dr * DIM + c;
        atomicAdd(drow + 0, v * x.x);
        atomicAdd(drow + 1, v * x.y);
        atomicAdd(drow + 2, v * x.z);
        atomicAdd(drow + 3, v * x.w);
    }
}

// ---------------------------------------------------------------------------
// Fused extraction + pooling + ratings. One 64-lane wave per batch element.
// ---------------------------------------------------------------------------
__global__ void out_fused_kernel(const float* __restrict__ user_emb,
                                 const float* __restrict__ item_emb,
                                 const int* __restrict__ users,
                                 const int* __restrict__ items,
                                 const int* __restrict__ c1, const int* __restrict__ c2,
                                 const int* __restrict__ c3,
                                 const float* __restrict__ pool,
                                 float* __restrict__ ratings,
                                 float* __restrict__ inter,
                                 float* __restrict__ inter_layers) {
    int b = blockIdx.x * 4 + (threadIdx.x >> 6);
    int d = threadIdx.x & 63;
    if (b >= BATCH) return;
    int un = users[b];
    int in_node = N_USER + items[b];

    int r1u = max(c1[un], 0), r1i = max(c1[in_node], 0);
    int r2u = max(c2[un], 0), r2i = max(c2[in_node], 0);
    int r3u = max(c3[un], 0), r3i = max(c3[in_node], 0);

    float u0 = user_emb[(size_t)un * DIM + d];
    float i0 = item_emb[(size_t)items[b] * DIM + d];
    float u1 = pool[(size_t)r1u * DIM + d];
    float i1 = pool[(size_t)r1i * DIM + d];
    float u2 = pool[(size_t)r2u * DIM + d];
    float i2 = pool[(size_t)r2i * DIM + d];
    float u3 = pool[(size_t)r3u * DIM + d];
    float i3 = pool[(size_t)r3i * DIM + d];

    size_t base = (size_t)b * 4 * DIM + d;
    inter_layers[base + 0 * DIM] = u0 * i0;
    inter_layers[base + 1 * DIM] = u1 * i1;
    inter_layers[base + 2 * DIM] = u2 * i2;
    inter_layers[base + 3 * DIM] = u3 * i3;

    float lu = (u0 + u1 + u2 + u3) * 0.25f;
    float li = (i0 + i1 + i2 + i3) * 0.25f;
    float p = lu * li;
    inter[(size_t)b * DIM + d] = p;
    float s = p;
#pragma unroll
    for (int off = 32; off > 0; off >>= 1) s += __shfl_down(s, off, 64);
    if (d == 0) ratings[b] = 1.0f / (1.0f + expf(-s));
}

// ---------------------------------------------------------------------------
extern "C" void kernel_launch(void* const* d_in, const int* in_sizes, int n_in,
                              void* d_out, int out_size, void* d_ws, size_t ws_size,
                              hipStream_t stream) {
    const float* user_emb  = (const float*)d_in[0];
    const float* item_emb  = (const float*)d_in[1];
    const float* edge_vals = (const float*)d_in[2];
    const int*   edge_src  = (const int*)d_in[3];
    const int*   edge_dst  = (const int*)d_in[4];
    const int*   users     = (const int*)d_in[5];
    const int*   items     = (const int*)d_in[6];

    float* out          = (float*)d_out;
    float* ratings      = out;                       // [BATCH]
    float* inter        = out + BATCH;               // [BATCH, DIM]
    float* inter_layers = out + BATCH + BATCH * DIM; // [BATCH, 4, DIM]

    char* ws = (char*)d_ws;
    size_t off = 0;
    int* c1 = (int*)(ws + off); off += (size_t)N_NODES * sizeof(int);
    int* c2 = (int*)(ws + off); off += (size_t)N_NODES * sizeof(int);
    int* c3 = (int*)(ws + off); off += (size_t)N_NODES * sizeof(int);
    float* pool = (float*)(ws + off); off += (size_t)POOLROWS * DIM * sizeof(float);
    int* mapCnt = (int*)(ws + off); off += 1024 * sizeof(int);
    int4* edgeCnt = (int4*)(ws + off); off += 512 * sizeof(int4);
    int4* cuts = (int4*)(ws + off); off += sizeof(int4);
    int* el_src = (int*)(ws + off); off += CAPE * sizeof(int);
    int* el_dst = (int*)(ws + off); off += CAPE * sizeof(int);
    float* el_v = (float*)(ws + off); off += CAPE * sizeof(float);

    const dim3 blk(256);
    const dim3 egrid((N_EDGES + 255) / 256);

    fill_init_kernel<<<2048, blk, 0, stream>>>((int4*)c1, (float4*)pool);

    seed_mark_kernel<<<(2 * BATCH + 255) / 256, blk, 0, stream>>>(
        users, items, c1, c2, c3);

    markA_kernel<<<egrid, blk, 0, stream>>>(edge_src, edge_dst, edge_vals, c3, c2, c1);
    markB_kernel<<<egrid, blk, 0, stream>>>(edge_src, edge_dst, edge_vals, c2, c1);

    count_kernel<<<NBLK_M + NBLK_E, blk, 0, stream>>>(
        c1, edge_dst, edge_vals, c1, c2, c3, mapCnt, edgeCnt);
    offsets_kernel<<<1, 1024, 0, stream>>>(mapCnt, edgeCnt, cuts);
    assign_scatter_kernel<<<NBLK_M + NBLK_E, blk, 0, stream>>>(
        c1, mapCnt, edgeCnt, edge_src, edge_dst, edge_vals,
        c1, c2, c3, el_src, el_dst, el_v);

    comp1_kernel<<<512, blk, 0, stream>>>(user_emb, item_emb, c1,
                                          el_src, el_dst, el_v, cuts, pool);
    comp_level_kernel<<<512, blk, 0, stream>>>(c1, c2, el_src, el_dst, el_v,
                                               cuts, 2, pool);
    comp_level_kernel<<<512, blk, 0, stream>>>(c2, c3, el_src, el_dst, el_v,
                                               cuts, 3, pool);

    out_fused_kernel<<<BATCH / 4, blk, 0, stream>>>(
        user_emb, item_emb, users, items, c1, c2, c3, pool,
        ratings, inter, inter_layers);
}

// Round 9
// 170.981 us; speedup vs baseline: 6.3039x; 1.0752x over previous
//
#include <hip/hip_runtime.h>

#define N_USER   300000
#define M_ITEM   700000
#define N_NODES  (N_USER + M_ITEM)
#define DIM      64
#define N_EDGES  1200000
#define BATCH    4096

#define POOLROWS 131072          // pooled rows, need ~59K
#define CAPE     131072          // edge entries per class segment, need ~40K max
#define SCHUNK   4096
#define NBLK_M   ((N_NODES + SCHUNK - 1) / SCHUNK)   // 245 map blocks
#define NBLK_E   ((N_EDGES + SCHUNK - 1) / SCHUNK)   // 293 edge blocks

// counters (64B-padded to avoid same-line serialization)
#define C_ROW 0
#define C_N3  16
#define C_N2  32
#define C_N1  48

// map encoding: 0 = unmarked; 1..3 = raw mark level m; (m<<24)|base = assigned.
__device__ __forceinline__ int level_of(int x) {
    return (x >= (1 << 24)) ? (x >> 24) : x;   // works for raw and packed; 0 -> 0
}

// ---------------------------------------------------------------------------
// Threefry2x32-20, JAX partitionable path (bit-exact, verified round 2).
// ---------------------------------------------------------------------------
__device__ __forceinline__ unsigned rotl32(unsigned x, int r) {
    return (x << r) | (x >> (32 - r));
}

__device__ __forceinline__ float edge_veff(int e, const float* __restrict__ evals) {
    unsigned ks[3] = {0u, 42u, 0u ^ 42u ^ 0x1BD11BDAu};
    unsigned x0 = ks[0];
    unsigned x1 = (unsigned)e + ks[1];
    const int rotA[4] = {13, 15, 26, 6};
    const int rotB[4] = {17, 29, 16, 24};
#pragma unroll
    for (int g = 0; g < 5; ++g) {
#pragma unroll
        for (int j = 0; j < 4; ++j) {
            int r = (g & 1) ? rotB[j] : rotA[j];
            x0 += x1;
            x1 = rotl32(x1, r);
            x1 ^= x0;
        }
        x0 += ks[(g + 1) % 3];
        x1 += ks[(g + 2) % 3] + (unsigned)(g + 1);
    }
    unsigned bits = x0 ^ x1;
    float u = __uint_as_float((bits >> 9) | 0x3F800000u) - 1.0f;
    return (u >= 0.1f) ? evals[e] * (1.0f / 0.9f) : 0.0f;
}

// ---------------------------------------------------------------------------
// Init: zero the 4MB map + counters. Grid-stride int4.
// ---------------------------------------------------------------------------
__global__ void fill_kernel(int4* __restrict__ map4, int* __restrict__ cnt) {
    const int MAP4 = N_NODES / 4;  // 250,000
    int tid = blockIdx.x * blockDim.x + threadIdx.x;
    int stride = gridDim.x * blockDim.x;
    int4 z = make_int4(0, 0, 0, 0);
    for (int i = tid; i < MAP4; i += stride) map4[i] = z;
    if (blockIdx.x == 0 && threadIdx.x < 64) cnt[threadIdx.x] = 0;
}

// ---------------------------------------------------------------------------
// Seed: sampled nodes get m=3 (plain store; all writers write 3).
// ---------------------------------------------------------------------------
__global__ void seed_kernel(const int* __restrict__ users,
                            const int* __restrict__ items,
                            int* __restrict__ map) {
    int t = blockIdx.x * blockDim.x + threadIdx.x;
    if (t >= 2 * BATCH) return;
    int node = (t < BATCH) ? users[t] : (N_USER + items[t - BATCH]);
    map[node] = 3;
}

// ---------------------------------------------------------------------------
// markA: edges with m(dst)==3 (seeds) & kept -> atomicMax(m[src], 2).
// markB: edges with m(dst)>=2 & kept        -> atomicMax(m[src], 1).
// 16 edges/thread, contiguous int4 edst loads; veff only on membership hit.
// Tests are stable mid-kernel: markA writes only 2s (test ==3), markB writes
// only 1s (test >=2). atomicMax never lowers a seed's 3.
// ---------------------------------------------------------------------------
__global__ void markA_kernel(const int* __restrict__ esrc, const int* __restrict__ edst,
                             const float* __restrict__ evals, int* __restrict__ map) {
    int base = (blockIdx.x * blockDim.x + threadIdx.x) * 16;
    if (base >= N_EDGES) return;
#pragma unroll
    for (int j = 0; j < 16; ++j) {
        int e = base + j;
        if (map[edst[e]] != 3) continue;
        if (edge_veff(e, evals) == 0.0f) continue;
        atomicMax(&map[esrc[e]], 2);
    }
}

__global__ void markB_kernel(const int* __restrict__ esrc, const int* __restrict__ edst,
                             const float* __restrict__ evals, int* __restrict__ map) {
    int base = (blockIdx.x * blockDim.x + threadIdx.x) * 16;
    if (base >= N_EDGES) return;
#pragma unroll
    for (int j = 0; j < 16; ++j) {
        int e = base + j;
        if (map[edst[e]] < 2) continue;
        if (edge_veff(e, evals) == 0.0f) continue;
        atomicMax(&map[esrc[e]], 1);
    }
}

// ---------------------------------------------------------------------------
// Fused assign: map blocks [0,245) allocate pool rows (block-aggregated
// atomicAdd on C_ROW), pack map entries to (m<<24)|base, and zero the rows.
// Edge blocks [245,538) class edges by level(m(dst)), append (src,dst,veff)
// to the class segment (block-aggregated atomics on C_N3/C_N2/C_N1).
// Mid-kernel map reads by edge blocks see raw m or packed - level_of handles
// both, and stale cross-XCD reads give raw m, which is still correct.
// ---------------------------------------------------------------------------
__global__ void assign_kernel(int* __restrict__ map,
                              const int* __restrict__ esrc,
                              const int* __restrict__ edst,
                              const float* __restrict__ evals,
                              int* __restrict__ cnt,
                              float* __restrict__ pool,
                              int* __restrict__ el_src, int* __restrict__ el_dst,
                              float* __restrict__ el_v) {
    int b = blockIdx.x, t = threadIdx.x;
    int lane = t & 63, w = t >> 6;
    __shared__ int ws[4], w1s[4], sbase[4];

    if (b < NBLK_M) {
        int base = b * SCHUNK + t * 16;
        int m[16];
        int s = 0;
#pragma unroll
        for (int j = 0; j < 16; ++j) {
            int i = base + j;
            m[j] = (i < N_NODES) ? map[i] : 0;   // raw 0..3 here (first packer)
            s += m[j];
        }
        int x = s;
#pragma unroll
        for (int off = 1; off < 64; off <<= 1) {
            int y = __shfl_up(x, off, 64);
            if (lane >= off) x += y;
        }
        if (lane == 63) ws[w] = x;
        __syncthreads();
        int woff = 0;
        for (int i = 0; i < w; ++i) woff += ws[i];
        if (t == 0) sbase[0] = atomicAdd(&cnt[C_ROW], ws[0] + ws[1] + ws[2] + ws[3]);
        __syncthreads();
        int run = sbase[0] + woff + (x - s);
        float4 z = {0.f, 0.f, 0.f, 0.f};
#pragma unroll
        for (int j = 0; j < 16; ++j) {
            if (!m[j]) continue;
            int i = base + j;
            int r = run; run += m[j];
            if (r + m[j] <= POOLROWS) {
                map[i] = (m[j] << 24) | r;
                float4* p4 = (float4*)(pool + (size_t)r * DIM);
                for (int k = 0; k < m[j] * 16; ++k) p4[k] = z;
            } else {
                map[i] = 0;  // defensive; never hit at these sizes
            }
        }
    } else {
        int base = (b - NBLK_M) * SCHUNK + t * 16;
        int lv[16]; float vv[16];
        int s3 = 0, s2 = 0, s1 = 0;
#pragma unroll
        for (int j = 0; j < 16; ++j) {
            lv[j] = 0; vv[j] = 0.f;
            int e = base + j;
            if (e >= N_EDGES) continue;
            int l = level_of(map[edst[e]]);
            if (!l) continue;
            float v = edge_veff(e, evals);
            if (v == 0.0f) continue;
            lv[j] = l; vv[j] = v;
            if (l == 3) s3++; else if (l == 2) s2++; else s1++;
        }
        int p = (s3 << 16) | s2;   // block sums <= 4096/field: no carry
        int x = p, x1 = s1;
#pragma unroll
        for (int off = 1; off < 64; off <<= 1) {
            int y = __shfl_up(x, off, 64);
            int y1 = __shfl_up(x1, off, 64);
            if (lane >= off) { x += y; x1 += y1; }
        }
        if (lane == 63) { ws[w] = x; w1s[w] = x1; }
        __syncthreads();
        int wo = 0, wo1 = 0;
        for (int i = 0; i < w; ++i) { wo += ws[i]; wo1 += w1s[i]; }
        if (t == 0) {
            int tp = ws[0] + ws[1] + ws[2] + ws[3];
            int t1 = w1s[0] + w1s[1] + w1s[2] + w1s[3];
            sbase[1] = atomicAdd(&cnt[C_N3], tp >> 16);
            sbase[2] = atomicAdd(&cnt[C_N2], tp & 0xFFFF);
            sbase[3] = atomicAdd(&cnt[C_N1], t1);
        }
        __syncthreads();
        int ex = wo + (x - p);
        int r3 = sbase[1] + (ex >> 16);
        int r2 = sbase[2] + (ex & 0xFFFF);
        int r1 = sbase[3] + wo1 + (x1 - s1);
#pragma unroll
        for (int j = 0; j < 16; ++j) {
            if (!lv[j]) continue;
            int e = base + j, pos;
            if (lv[j] == 3)      pos = 0 * CAPE + (r3++);
            else if (lv[j] == 2) pos = 1 * CAPE + (r2++);
            else                 pos = 2 * CAPE + (r1++);
            if ((pos & (CAPE - 1)) < CAPE) {  // always true; segment-local overflow
                el_src[pos] = esrc[e];
                el_dst[pos] = edst[e];
                el_v[pos]   = vv[j];
            }
        }
    }
}

// ---------------------------------------------------------------------------
// comp1: level-1 propagation for ALL listed edges (el3+el2+el1):
//   pool[base(dst)] += v * raw_input[src]
// ---------------------------------------------------------------------------
__global__ void comp1_kernel(const float* __restrict__ src_user,
                             const float* __restrict__ src_item,
                             const int* __restrict__ map,
                             const int* __restrict__ el_src,
                             const int* __restrict__ el_dst,
                             const float* __restrict__ el_v,
                             const int* __restrict__ cnt,
                             float* __restrict__ pool) {
    int n3 = min(cnt[C_N3], CAPE), n2 = min(cnt[C_N2], CAPE), n1 = min(cnt[C_N1], CAPE);
    int total = (n3 + n2 + n1) * 16;
    int stride = gridDim.x * blockDim.x;
    for (int t = blockIdx.x * blockDim.x + threadIdx.x; t < total; t += stride) {
        int e = t >> 4, c = (t & 15) << 2;
        int i = (e < n3) ? e : (e < n3 + n2) ? (e - n3 + CAPE) : (e - n3 - n2 + 2 * CAPE);
        int s = el_src[i];
        int xd = map[el_dst[i]];
        if (xd < (1 << 24)) continue;  // defensive
        int dr = xd & 0xFFFFFF;
        float v = el_v[i];
        const float* srow = (s < N_USER) ? (src_user + (size_t)s * DIM)
                                         : (src_item + (size_t)(s - N_USER) * DIM);
        float4 xv = *(const float4*)(srow + c);
        float* drow = pool + (size_t)dr * DIM + c;
        atomicAdd(drow + 0, v * xv.x);
        atomicAdd(drow + 1, v * xv.y);
        atomicAdd(drow + 2, v * xv.z);
        atomicAdd(drow + 3, v * xv.w);
    }
}

// ---------------------------------------------------------------------------
// comp2 (which=2): edges with m(dst)>=2 (el3+el2): pool[base(d)+1] += v*pool[base(s)]
// comp3 (which=3): el3 only:                       pool[base(d)+2] += v*pool[base(s)+1]
// ---------------------------------------------------------------------------
__global__ void comp23_kernel(const int* __restrict__ map,
                              const int* __restrict__ el_src,
                              const int* __restrict__ el_dst,
                              const float* __restrict__ el_v,
                              const int* __restrict__ cnt, int which,
                              float* __restrict__ pool) {
    int n3 = min(cnt[C_N3], CAPE), n2 = min(cnt[C_N2], CAPE);
    int lim = (which == 2) ? (n3 + n2) : n3;
    int total = lim * 16;
    int stride = gridDim.x * blockDim.x;
    for (int t = blockIdx.x * blockDim.x + threadIdx.x; t < total; t += stride) {
        int e = t >> 4, c = (t & 15) << 2;
        int i = (e < n3) ? e : (e - n3 + CAPE);
        int xs = map[el_src[i]];
        int xd = map[el_dst[i]];
        if (xs < (1 << 24) || xd < (1 << 24)) continue;  // defensive
        int sr = (xs & 0xFFFFFF) + (which - 2);
        int dr = (xd & 0xFFFFFF) + (which - 1);
        float v = el_v[i];
        float4 xv = *(const float4*)(pool + (size_t)sr * DIM + c);
        float* drow = pool + (size_t)dr * DIM + c;
        atomicAdd(drow + 0, v * xv.x);
        atomicAdd(drow + 1, v * xv.y);
        atomicAdd(drow + 2, v * xv.z);
        atomicAdd(drow + 3, v * xv.w);
    }
}

// ---------------------------------------------------------------------------
// Fused extraction + pooling + ratings. One 64-lane wave per batch element.
// Sampled nodes have m=3: rows base, base+1, base+2.
// ---------------------------------------------------------------------------
__global__ void out_fused_kernel(const float* __restrict__ user_emb,
                                 const float* __restrict__ item_emb,
                                 const int* __restrict__ users,
                                 const int* __restrict__ items,
                                 const int* __restrict__ map,
                                 const float* __restrict__ pool,
                                 float* __restrict__ ratings,
                                 float* __restrict__ inter,
                                 float* __restrict__ inter_layers) {
    int b = blockIdx.x * 4 + (threadIdx.x >> 6);
    int d = threadIdx.x & 63;
    if (b >= BATCH) return;
    int un = users[b];
    int in_node = N_USER + items[b];
    int ru = map[un] & 0xFFFFFF;
    int ri = map[in_node] & 0xFFFFFF;

    float u0 = user_emb[(size_t)un * DIM + d];
    float i0 = item_emb[(size_t)items[b] * DIM + d];
    float u1 = pool[(size_t)(ru + 0) * DIM + d];
    float u2 = pool[(size_t)(ru + 1) * DIM + d];
    float u3 = pool[(size_t)(ru + 2) * DIM + d];
    float i1 = pool[(size_t)(ri + 0) * DIM + d];
    float i2 = pool[(size_t)(ri + 1) * DIM + d];
    float i3 = pool[(size_t)(ri + 2) * DIM + d];

    size_t base = (size_t)b * 4 * DIM + d;
    inter_layers[base + 0 * DIM] = u0 * i0;
    inter_layers[base + 1 * DIM] = u1 * i1;
    inter_layers[base + 2 * DIM] = u2 * i2;
    inter_layers[base + 3 * DIM] = u3 * i3;

    float lu = (u0 + u1 + u2 + u3) * 0.25f;
    float li = (i0 + i1 + i2 + i3) * 0.25f;
    float p = lu * li;
    inter[(size_t)b * DIM + d] = p;
    float s = p;
#pragma unroll
    for (int off = 32; off > 0; off >>= 1) s += __shfl_down(s, off, 64);
    if (d == 0) ratings[b] = 1.0f / (1.0f + expf(-s));
}

// ---------------------------------------------------------------------------
extern "C" void kernel_launch(void* const* d_in, const int* in_sizes, int n_in,
                              void* d_out, int out_size, void* d_ws, size_t ws_size,
                              hipStream_t stream) {
    const float* user_emb  = (const float*)d_in[0];
    const float* item_emb  = (const float*)d_in[1];
    const float* edge_vals = (const float*)d_in[2];
    const int*   edge_src  = (const int*)d_in[3];
    const int*   edge_dst  = (const int*)d_in[4];
    const int*   users     = (const int*)d_in[5];
    const int*   items     = (const int*)d_in[6];

    float* out          = (float*)d_out;
    float* ratings      = out;                       // [BATCH]
    float* inter        = out + BATCH;               // [BATCH, DIM]
    float* inter_layers = out + BATCH + BATCH * DIM; // [BATCH, 4, DIM]

    char* ws = (char*)d_ws;
    size_t off = 0;
    int* map = (int*)(ws + off); off += (size_t)N_NODES * sizeof(int);
    float* pool = (float*)(ws + off); off += (size_t)POOLROWS * DIM * sizeof(float);
    int* cnt = (int*)(ws + off); off += 256 * sizeof(int);
    int* el_src = (int*)(ws + off); off += (size_t)3 * CAPE * sizeof(int);
    int* el_dst = (int*)(ws + off); off += (size_t)3 * CAPE * sizeof(int);
    float* el_v = (float*)(ws + off); off += (size_t)3 * CAPE * sizeof(float);

    const dim3 blk(256);
    const dim3 mgrid((N_EDGES / 16 + 255) / 256);  // 293 blocks, 16 edges/thread

    fill_kernel<<<512, blk, 0, stream>>>((int4*)map, cnt);
    seed_kernel<<<(2 * BATCH + 255) / 256, blk, 0, stream>>>(users, items, map);
    markA_kernel<<<mgrid, blk, 0, stream>>>(edge_src, edge_dst, edge_vals, map);
    markB_kernel<<<mgrid, blk, 0, stream>>>(edge_src, edge_dst, edge_vals, map);
    assign_kernel<<<NBLK_M + NBLK_E, blk, 0, stream>>>(
        map, edge_src, edge_dst, edge_vals, cnt, pool, el_src, el_dst, el_v);
    comp1_kernel<<<1024, blk, 0, stream>>>(user_emb, item_emb, map,
                                           el_src, el_dst, el_v, cnt, pool);
    comp23_kernel<<<512, blk, 0, stream>>>(map, el_src, el_dst, el_v, cnt, 2, pool);
    comp23_kernel<<<512, blk, 0, stream>>>(map, el_src, el_dst, el_v, cnt, 3, pool);
    out_fused_kernel<<<BATCH / 4, blk, 0, stream>>>(
        user_emb, item_emb, users, items, map, pool, ratings, inter, inter_layers);
}